// Round 11
// baseline (596.242 us; speedup 1.0000x reference)
//
#include <hip/hip_runtime.h>

// 2-layer LSTM (HID=10), B=2048, T=1024 main + F=64 future steps.
// P=10: lane (e,u) owns all 4 gate rows of unit u; EPW=6 elements/wave;
// 342 single-wave blocks. Weights prescaled+pinned (waves_per_eu(1,1)).
//
// Round 11: DEEPER SKEW. r9/r10 measurements fit: bperm stage ~150 lat +
// ~11/op issue; post-bcast dot issue sits on the chain; time = 1088 x chain.
// r10's chain (~1147): both cells wait one combined 20-bperm batch, then
// 168 fma of dots issue before acts. Now cell2 is delayed ONE MORE step:
// iter n = cell1(n) [h1(n) fresh] + cell2 step n-2 [h1(n-1) reg copy,
// h2(n-2) one-iter-old bcast]. Broadcasts issue as two ordered batches
// (h1 first); consumers ordered so cell1 dots wait only the h1 batch.
// Critical loop = h1 self-recurrence only: bcast(~260) + 44 fma + act +
// c + ctanh ~= 620 cyc. Everything else has >= 1 iter of slack.
// y emerges 3 iters late -> scalar stores, peeled prologue/epilogue.

#define NB 2048
#define TMAIN 1024
#define HID 10
#define EPW 6

#define PIN(v) asm volatile("" : "+v"(v))

__device__ __forceinline__ float rcp_(float v)  { return __builtin_amdgcn_rcpf(v); }
__device__ __forceinline__ float exp2_(float v) { return __builtin_amdgcn_exp2f(v); }

__global__ __launch_bounds__(64)
__attribute__((amdgpu_waves_per_eu(1, 1)))
void lstm2_kernel(
    const float* __restrict__ x,
    const float* __restrict__ Wih1, const float* __restrict__ Whh1,
    const float* __restrict__ bih1, const float* __restrict__ bhh1,
    const float* __restrict__ Wih2, const float* __restrict__ Whh2,
    const float* __restrict__ bih2, const float* __restrict__ bhh2,
    const float* __restrict__ Wlin, const float* __restrict__ blin,
    const int* __restrict__ futp,
    float* __restrict__ out)
{
    const int lane = threadIdx.x;
    const int blk  = blockIdx.x;
    const int F    = futp[0];
    const int OUTW = TMAIN + F;

    const float LOG2E = 1.4426950408889634f;
    const float tK    = 2.0f * LOG2E;

    int e_raw = lane / HID;
    const int u = lane - e_raw * HID;
    const int e = (e_raw < EPW) ? e_raw : 0;      // lanes 60..63 shadow element 0
    const int ge  = blk * EPW + e;
    const int gec = (ge < NB) ? ge : (NB - 1);
    const bool outOK = (e_raw < EPW) && (ge < NB) && (u == 0);
    const int ebase = e * HID;

    int baddr[HID];
    #pragma unroll
    for (int j = 0; j < HID; ++j) baddr[j] = (ebase + j) * 4;

    // ---- per-lane weights: 4 gate rows of unit u, prescaled per row ----
    float w1[4][HID], wi2[4][HID], wh2[4][HID], wx[4], b1[4], b2[4];
    float wl[HID], bl;
    #pragma unroll
    for (int k = 0; k < 4; ++k) {
        const float K = (k == 2) ? tK : -LOG2E;
        const int r = k * HID + u;
        wx[k] = Wih1[r] * K;
        b1[k] = (bih1[r] + bhh1[r]) * K;
        b2[k] = (bih2[r] + bhh2[r]) * K;
        #pragma unroll
        for (int j = 0; j < HID; ++j) {
            w1[k][j]  = Whh1[r * HID + j] * K;
            wi2[k][j] = Wih2[r * HID + j] * K;
            wh2[k][j] = Whh2[r * HID + j] * K;
        }
    }
    #pragma unroll
    for (int j = 0; j < HID; ++j) wl[j] = Wlin[j];
    bl = blin[0];

    #pragma unroll
    for (int k = 0; k < 4; ++k) {
        PIN(wx[k]); PIN(b1[k]); PIN(b2[k]);
        #pragma unroll
        for (int j = 0; j < HID; ++j) { PIN(w1[k][j]); PIN(wi2[k][j]); PIN(wh2[k][j]); }
    }
    #pragma unroll
    for (int j = 0; j < HID; ++j) PIN(wl[j]);
    PIN(bl);

    auto bp = [](int addr, float v) -> float {
        return __int_as_float(__builtin_amdgcn_ds_bpermute(addr, __float_as_int(v)));
    };
    auto actS = [&](float p) -> float { return rcp_(1.0f + exp2_(p)); };          // sigmoid
    auto actG = [&](float p) -> float { return fmaf(-2.0f * tK, rcp_(1.0f + exp2_(p)), tK); }; // tK*tanh
    auto ctanh = [&](float cs) -> float { return fmaf(-2.0f, rcp_(1.0f + exp2_(cs)), 1.0f); };

    // ---- state ----
    // h1b = h1(n) (fresh bcast), h1o = h1(n-1) (reg copy), h2b = h2(n-2) (fresh)
    // c1 carries tK*c1(n); c2 carries tK*c2(n-2)
    float c1 = 0.f, c2 = 0.f;
    float h1b[HID], h1o[HID], h2b[HID];
    #pragma unroll
    for (int j = 0; j < HID; ++j) { h1b[j] = 0.f; h1o[j] = 0.f; h2b[j] = 0.f; }

    float* orow = out + (size_t)ge * OUTW;

    // cell1-only iteration (prologue n=0,1): h1(n+1) from (x_n, h1(n)); rotate.
    auto c1_iter = [&](float xt) {
        float p[4];
        #pragma unroll
        for (int k = 0; k < 4; ++k) {
            float s0 = fmaf(xt, wx[k], b1[k]);
            float s1 = h1b[5] * w1[k][5];
            #pragma unroll
            for (int j = 0; j < 5; ++j) {
                s0 = fmaf(h1b[j], w1[k][j], s0);
                if (j) s1 = fmaf(h1b[5 + j], w1[k][5 + j], s1);
            }
            p[k] = s0 + s1;
        }
        float pi = actS(p[0]), pf = actS(p[1]), pg = actG(p[2]), po = actS(p[3]);
        c1 = fmaf(pf, c1, pi * pg);
        float h1u = po * ctanh(c1);
        #pragma unroll
        for (int j = 0; j < HID; ++j) { h1o[j] = h1b[j]; h1b[j] = bp(baddr[j], h1u); }
    };

    // full steady iteration n: cell1(n) + head(y_{n-3}) + cell2 step n-2.
    auto full_iter = [&](float xt, int yi) {
        // ---- cell1: consumes h1b (waits h1 batch only) ----
        float p[4];
        #pragma unroll
        for (int k = 0; k < 4; ++k) {
            float s0 = fmaf(xt, wx[k], b1[k]);
            float s1 = h1b[5] * w1[k][5];
            #pragma unroll
            for (int j = 0; j < 5; ++j) {
                s0 = fmaf(h1b[j], w1[k][j], s0);
                if (j) s1 = fmaf(h1b[5 + j], w1[k][5 + j], s1);
            }
            p[k] = s0 + s1;
        }
        float pi = actS(p[0]), pf = actS(p[1]), pg = actG(p[2]), po = actS(p[3]);
        c1 = fmaf(pf, c1, pi * pg);
        float h1u = po * ctanh(c1);
        float h1n[HID];
        #pragma unroll
        for (int j = 0; j < HID; ++j) { h1n[j] = h1b[j]; h1b[j] = bp(baddr[j], h1u); }

        // ---- head: consumes h2b (waits h2 batch) ----
        float y0 = fmaf(h2b[0], wl[0], bl);
        float y1 = h2b[5] * wl[5];
        #pragma unroll
        for (int j = 1; j < 5; ++j) {
            y0 = fmaf(h2b[j], wl[j], y0);
            y1 = fmaf(h2b[5 + j], wl[5 + j], y1);
        }
        float y = y0 + y1;
        if (outOK && yi >= 0) orow[yi] = y;

        // ---- cell2 step n-2: h1o (regs) + h2b (fresh) ----
        float q[4];
        #pragma unroll
        for (int k = 0; k < 4; ++k) {
            float s0 = b2[k];
            float s1 = h1o[5] * wi2[k][5];
            float s2 = h2b[0] * wh2[k][0];
            float s3 = h2b[5] * wh2[k][5];
            #pragma unroll
            for (int j = 0; j < 5; ++j) {
                s0 = fmaf(h1o[j], wi2[k][j], s0);
                if (j) s1 = fmaf(h1o[5 + j], wi2[k][5 + j], s1);
                if (j) s2 = fmaf(h2b[j],     wh2[k][j],     s2);
                if (j) s3 = fmaf(h2b[5 + j], wh2[k][5 + j], s3);
            }
            q[k] = (s0 + s1) + (s2 + s3);
        }
        float qi = actS(q[0]), qf = actS(q[1]), qg = actG(q[2]), qo = actS(q[3]);
        c2 = fmaf(qf, c2, qi * qg);
        float h2u = qo * ctanh(c2);
        #pragma unroll
        for (int j = 0; j < HID; ++j) h2b[j] = bp(baddr[j], h2u);
        // rotate h1 history
        #pragma unroll
        for (int j = 0; j < HID; ++j) h1o[j] = h1n[j];
    };

    // cell2-only (epilogue): head(y yi) + cell2 from (hs, h2b fresh)
    auto c2_iter = [&](const float (&hs)[HID], int yi) {
        float y0 = fmaf(h2b[0], wl[0], bl);
        float y1 = h2b[5] * wl[5];
        #pragma unroll
        for (int j = 1; j < 5; ++j) {
            y0 = fmaf(h2b[j], wl[j], y0);
            y1 = fmaf(h2b[5 + j], wl[5 + j], y1);
        }
        if (outOK) orow[yi] = y0 + y1;
        float q[4];
        #pragma unroll
        for (int k = 0; k < 4; ++k) {
            float s0 = b2[k];
            float s1 = hs[5] * wi2[k][5];
            float s2 = h2b[0] * wh2[k][0];
            float s3 = h2b[5] * wh2[k][5];
            #pragma unroll
            for (int j = 0; j < 5; ++j) {
                s0 = fmaf(hs[j], wi2[k][j], s0);
                if (j) s1 = fmaf(hs[5 + j], wi2[k][5 + j], s1);
                if (j) s2 = fmaf(h2b[j],     wh2[k][j],     s2);
                if (j) s3 = fmaf(h2b[5 + j], wh2[k][5 + j], s3);
            }
            q[k] = (s0 + s1) + (s2 + s3);
        }
        float qi = actS(q[0]), qf = actS(q[1]), qg = actG(q[2]), qo = actS(q[3]);
        c2 = fmaf(qf, c2, qi * qg);
        float h2u = qo * ctanh(c2);
        #pragma unroll
        for (int j = 0; j < HID; ++j) h2b[j] = bp(baddr[j], h2u);
    };

    // serial step for the future loop
    auto fstep = [&](float xt) -> float {
        float p[4];
        #pragma unroll
        for (int k = 0; k < 4; ++k) {
            float s0 = fmaf(xt, wx[k], b1[k]);
            float s1 = h1b[5] * w1[k][5];
            #pragma unroll
            for (int j = 0; j < 5; ++j) {
                s0 = fmaf(h1b[j], w1[k][j], s0);
                if (j) s1 = fmaf(h1b[5 + j], w1[k][5 + j], s1);
            }
            p[k] = s0 + s1;
        }
        float pi = actS(p[0]), pf = actS(p[1]), pg = actG(p[2]), po = actS(p[3]);
        c1 = fmaf(pf, c1, pi * pg);
        float h1u = po * ctanh(c1);
        #pragma unroll
        for (int j = 0; j < HID; ++j) h1b[j] = bp(baddr[j], h1u);
        float q[4];
        #pragma unroll
        for (int k = 0; k < 4; ++k) {
            float s0 = b2[k];
            float s1 = h1b[5] * wi2[k][5];
            float s2 = h2b[0] * wh2[k][0];
            float s3 = h2b[5] * wh2[k][5];
            #pragma unroll
            for (int j = 0; j < 5; ++j) {
                s0 = fmaf(h1b[j], wi2[k][j], s0);
                if (j) s1 = fmaf(h1b[5 + j], wi2[k][5 + j], s1);
                if (j) s2 = fmaf(h2b[j],     wh2[k][j],     s2);
                if (j) s3 = fmaf(h2b[5 + j], wh2[k][5 + j], s3);
            }
            q[k] = (s0 + s1) + (s2 + s3);
        }
        float qi = actS(q[0]), qf = actS(q[1]), qg = actG(q[2]), qo = actS(q[3]);
        c2 = fmaf(qf, c2, qi * qg);
        float h2u = qo * ctanh(c2);
        #pragma unroll
        for (int j = 0; j < HID; ++j) h2b[j] = bp(baddr[j], h2u);
        float y0 = fmaf(h2b[0], wl[0], bl);
        float y1 = h2b[5] * wl[5];
        #pragma unroll
        for (int j = 1; j < 5; ++j) {
            y0 = fmaf(h2b[j], wl[j], y0);
            y1 = fmaf(h2b[5 + j], wl[5 + j], y1);
        }
        return y0 + y1;
    };

    // ---- prologue: n=0,1 (cell1 only) ----
    const float4* xrow = (const float4*)(x + (size_t)gec * TMAIN);
    float4 xa = xrow[0];
    c1_iter(xa.x);      // h1(1); h1o=h1(0)=0
    c1_iter(xa.y);      // h1(2); h1o=h1(1)

    // ---- steady: groups g=0..254 cover n=4g+2 .. 4g+5 (n=2..1021) ----
    #pragma unroll 1
    for (int g = 0; g < TMAIN / 4 - 1; ++g) {
        float4 xb = xrow[g + 1];
        int n = 4 * g + 2;
        full_iter(xa.z, n - 3);
        full_iter(xa.w, n - 2);
        full_iter(xb.x, n - 1);
        full_iter(xb.y, n);
        xa = xb;
    }
    // ---- epilogue ----
    full_iter(xa.z, 1019);          // n=1022: h1(1023), h2(1021), y1019
    full_iter(xa.w, 1020);          // n=1023: h1(1024), h2(1022), y1020
    c2_iter(h1o, 1021);             // n=1024: h2(1023), y1021   (h1o = h1(1023))
    c2_iter(h1b, 1022);             // n=1025: h2(1024), y1022   (h1b = h1(1024))
    {                                // n=1026: y1023 = head(h2(1024))
        float y0 = fmaf(h2b[0], wl[0], bl);
        float y1 = h2b[5] * wl[5];
        #pragma unroll
        for (int j = 1; j < 5; ++j) {
            y0 = fmaf(h2b[j], wl[j], y0);
            y1 = fmaf(h2b[5 + j], wl[5 + j], y1);
        }
        float ylast = y0 + y1;
        if (outOK) orow[TMAIN - 1] = ylast;
        // ---- future loop: serial; state = h1(1024), h2(1024), c1(1024), c2(1024) ----
        float yprev = ylast;
        #pragma unroll 1
        for (int t = 0; t < F; ++t) {
            yprev = fstep(yprev);
            if (outOK) orow[TMAIN + t] = yprev;
        }
    }
}

extern "C" void kernel_launch(void* const* d_in, const int* in_sizes, int n_in,
                              void* d_out, int out_size, void* d_ws, size_t ws_size,
                              hipStream_t stream) {
    const float* x    = (const float*)d_in[0];
    const float* Wih1 = (const float*)d_in[1];
    const float* Whh1 = (const float*)d_in[2];
    const float* bih1 = (const float*)d_in[3];
    const float* bhh1 = (const float*)d_in[4];
    const float* Wih2 = (const float*)d_in[5];
    const float* Whh2 = (const float*)d_in[6];
    const float* bih2 = (const float*)d_in[7];
    const float* bhh2 = (const float*)d_in[8];
    const float* Wlin = (const float*)d_in[9];
    const float* blin = (const float*)d_in[10];
    const int*   futp = (const int*)d_in[11];
    float* out = (float*)d_out;

    int grid = (NB + EPW - 1) / EPW;   // 342 single-wave blocks
    lstm2_kernel<<<grid, 64, 0, stream>>>(x, Wih1, Whh1, bih1, bhh1,
                                          Wih2, Whh2, bih2, bhh2,
                                          Wlin, blin, futp, out);
}

// Round 12
// 472.627 us; speedup vs baseline: 1.2616x; 1.2616x over previous
//
#include <hip/hip_runtime.h>

// 2-layer LSTM (HID=10), B=2048, T=1024 main + F=64 future steps.
// Round 12: P=40, one element per wave, 2048 blocks = 2 waves/SIMD on all
// 1024 SIMDs (the only regime where per-lane weights (43) truly fit in arch
// VGPRs -- every P=10 round hid ~124 weights in AGPRs, +1 accvgpr_read/use).
// Lane = 4*u + k (UNIT-MAJOR): unit u's four gates (i,f,g,o) occupy one
// QUAD -> f/g/o act gathers are v_mov_dpp quad_perm (VALU, ~4cyc) instead of
// ds_bpermute (+150cyc on the chain, twice/step). r11's skew: iter n runs
// cell1 step n+1 (fresh h1) and cell2 step n-1 (h1(n-1) reg copy, h2(n-2)
// one-iter-old bcast) -> every bperm broadcast has >=150cyc of independent
// issue before its consumer. One uniform activation path per cell.

#define NB 2048
#define TMAIN 1024
#define HID 10

#define PIN(v) asm volatile("" : "+v"(v))

__device__ __forceinline__ float rcp_(float v)  { return __builtin_amdgcn_rcpf(v); }
__device__ __forceinline__ float exp2_(float v) { return __builtin_amdgcn_exp2f(v); }
__device__ __forceinline__ float bp(int addr, float v) {
    return __int_as_float(__builtin_amdgcn_ds_bpermute(addr, __float_as_int(v)));
}
template<int CTRL>
__device__ __forceinline__ float qb(float v) {   // quad_perm broadcast within quad
    return __int_as_float(__builtin_amdgcn_update_dpp(
        0, __float_as_int(v), CTRL, 0xF, 0xF, false));
}

__global__ __launch_bounds__(64)
__attribute__((amdgpu_waves_per_eu(2, 2)))
void lstm2_kernel(
    const float* __restrict__ x,
    const float* __restrict__ Wih1, const float* __restrict__ Whh1,
    const float* __restrict__ bih1, const float* __restrict__ bhh1,
    const float* __restrict__ Wih2, const float* __restrict__ Whh2,
    const float* __restrict__ bih2, const float* __restrict__ bhh2,
    const float* __restrict__ Wlin, const float* __restrict__ blin,
    const int* __restrict__ futp,
    float* __restrict__ out)
{
    const int lane = threadIdx.x;
    const int ge   = blockIdx.x;             // one batch element per block
    const int F    = futp[0];
    const int OUTW = TMAIN + F;

    const float LOG2E = 1.4426950408889634f;
    const float tK    = 2.0f * LOG2E;

    const int L = (lane < 40) ? lane : 0;    // lanes 40..63 shadow lane 0
    const int u = L >> 2;                    // hidden unit (quad index)
    const int k = L & 3;                     // gate: 0=i 1=f 2=g 3=o

    // uniform activation: act = aA + aB * rcp(1+exp2(p)), p prescaled by K
    const bool isg = (k == 2);
    const float K  = isg ?  tK : -LOG2E;
    const float aA = isg ?  tK : 0.0f;       // g-gate scaled by tK -> cell state
    const float aB = isg ? -2.0f * tK : 1.0f; // carries tK*c, ctanh needs no mul

    // ---- per-lane weights: gate row r = k*HID+u, prescaled by K ----
    float w1[HID], wi2[HID], wh2[HID], wl[HID];
    const int r = k * HID + u;
    #pragma unroll
    for (int j = 0; j < HID; ++j) {
        w1[j]  = Whh1[r * HID + j] * K;
        wi2[j] = Wih2[r * HID + j] * K;
        wh2[j] = Whh2[r * HID + j] * K;
        wl[j]  = Wlin[j];
    }
    float wx = Wih1[r] * K;
    float b1 = (bih1[r] + bhh1[r]) * K;
    float b2 = (bih2[r] + bhh2[r]) * K;
    float bl = blin[0];

    #pragma unroll
    for (int j = 0; j < HID; ++j) { PIN(w1[j]); PIN(wi2[j]); PIN(wh2[j]); PIN(wl[j]); }
    PIN(wx); PIN(b1); PIN(b2); PIN(bl);

    // broadcast source lanes: unit j's value lives in (all lanes of) quad j;
    // read lane 4j  -> bpermute byte addr 16j
    int baddr[HID];
    #pragma unroll
    for (int j = 0; j < HID; ++j) baddr[j] = 16 * j;

    auto actf = [&](float p) -> float { return fmaf(aB, rcp_(1.0f + exp2_(p)), aA); };
    auto ctanh = [&](float cs) -> float { return fmaf(-2.0f, rcp_(1.0f + exp2_(cs)), 1.0f); };

    // ---- state ----
    // h1b = h1(n) fresh bcast; h1o = h1(n-1) regs; h2b = h2(n-2) fresh bcast
    // c1 = tK*c1(n); c2 = tK*c2(n-2)   (valid on all lanes: quad-redundant)
    float c1 = 0.f, c2 = 0.f;
    float h1b[HID], h1o[HID], h2b[HID];
    #pragma unroll
    for (int j = 0; j < HID; ++j) { h1b[j] = 0.f; h1o[j] = 0.f; h2b[j] = 0.f; }

    float* orow = out + (size_t)ge * OUTW;
    const bool st = (lane == 0);

    // cell1-only iteration (prologue): h1(next) from (xt, h1b); rotate h1o.
    auto c1_iter = [&](float xt) {
        float s0 = fmaf(xt, wx, b1);
        float s1 = h1b[5] * w1[5];
        #pragma unroll
        for (int j = 0; j < 5; ++j) {
            s0 = fmaf(h1b[j], w1[j], s0);
            if (j) s1 = fmaf(h1b[5 + j], w1[5 + j], s1);
        }
        float a = actf(s0 + s1);
        float gi = qb<0x00>(a), gf = qb<0x55>(a), gg = qb<0xAA>(a), go = qb<0xFF>(a);
        c1 = fmaf(gf, c1, gi * gg);
        float h1u = go * ctanh(c1);
        #pragma unroll
        for (int j = 0; j < HID; ++j) { h1o[j] = h1b[j]; h1b[j] = bp(baddr[j], h1u); }
    };

    // steady iteration n: cell1 step n+1, head(y_{n-2} from h2b), cell2 step n-1.
    auto full_iter = [&](float xt, int yi) {
        // ---- cell1 (consumes h1b; bcast issued ~150+cyc ago) ----
        float s0 = fmaf(xt, wx, b1);
        float s1 = h1b[5] * w1[5];
        #pragma unroll
        for (int j = 0; j < 5; ++j) {
            s0 = fmaf(h1b[j], w1[j], s0);
            if (j) s1 = fmaf(h1b[5 + j], w1[5 + j], s1);
        }
        float a = actf(s0 + s1);
        float gi = qb<0x00>(a), gf = qb<0x55>(a), gg = qb<0xAA>(a), go = qb<0xFF>(a);
        c1 = fmaf(gf, c1, gi * gg);
        float h1u = go * ctanh(c1);
        float h1n[HID];
        #pragma unroll
        for (int j = 0; j < HID; ++j) { h1n[j] = h1b[j]; h1b[j] = bp(baddr[j], h1u); }

        // ---- head: y(n-2) = head(h2b) ----
        float y0 = fmaf(h2b[0], wl[0], bl);
        float y1 = h2b[5] * wl[5];
        #pragma unroll
        for (int j = 1; j < 5; ++j) {
            y0 = fmaf(h2b[j], wl[j], y0);
            y1 = fmaf(h2b[5 + j], wl[5 + j], y1);
        }
        if (st && yi >= 0) orow[yi] = y0 + y1;

        // ---- cell2 step n-1: h1o (regs) + h2b ----
        float q0 = b2;
        float q1 = h1o[5] * wi2[5];
        float q2 = h2b[0] * wh2[0];
        float q3 = h2b[5] * wh2[5];
        #pragma unroll
        for (int j = 0; j < 5; ++j) {
            q0 = fmaf(h1o[j], wi2[j], q0);
            if (j) q1 = fmaf(h1o[5 + j], wi2[5 + j], q1);
            if (j) q2 = fmaf(h2b[j],     wh2[j],     q2);
            if (j) q3 = fmaf(h2b[5 + j], wh2[5 + j], q3);
        }
        float d = actf((q0 + q1) + (q2 + q3));
        float qi = qb<0x00>(d), qf = qb<0x55>(d), qg = qb<0xAA>(d), qo = qb<0xFF>(d);
        c2 = fmaf(qf, c2, qi * qg);
        float h2u = qo * ctanh(c2);
        #pragma unroll
        for (int j = 0; j < HID; ++j) h2b[j] = bp(baddr[j], h2u);
        #pragma unroll
        for (int j = 0; j < HID; ++j) h1o[j] = h1n[j];
    };

    // epilogue: head(y yi from h2b) + cell2 from (hs, h2b)
    auto c2_iter = [&](const float (&hs)[HID], int yi) {
        float y0 = fmaf(h2b[0], wl[0], bl);
        float y1 = h2b[5] * wl[5];
        #pragma unroll
        for (int j = 1; j < 5; ++j) {
            y0 = fmaf(h2b[j], wl[j], y0);
            y1 = fmaf(h2b[5 + j], wl[5 + j], y1);
        }
        if (st) orow[yi] = y0 + y1;
        float q0 = b2;
        float q1 = hs[5] * wi2[5];
        float q2 = h2b[0] * wh2[0];
        float q3 = h2b[5] * wh2[5];
        #pragma unroll
        for (int j = 0; j < 5; ++j) {
            q0 = fmaf(hs[j], wi2[j], q0);
            if (j) q1 = fmaf(hs[5 + j], wi2[5 + j], q1);
            if (j) q2 = fmaf(h2b[j],     wh2[j],     q2);
            if (j) q3 = fmaf(h2b[5 + j], wh2[5 + j], q3);
        }
        float d = actf((q0 + q1) + (q2 + q3));
        float qi = qb<0x00>(d), qf = qb<0x55>(d), qg = qb<0xAA>(d), qo = qb<0xFF>(d);
        c2 = fmaf(qf, c2, qi * qg);
        float h2u = qo * ctanh(c2);
        #pragma unroll
        for (int j = 0; j < HID; ++j) h2b[j] = bp(baddr[j], h2u);
    };

    // serial step for the future loop (y feeds back)
    auto fstep = [&](float xt) -> float {
        float s0 = fmaf(xt, wx, b1);
        float s1 = h1b[5] * w1[5];
        #pragma unroll
        for (int j = 0; j < 5; ++j) {
            s0 = fmaf(h1b[j], w1[j], s0);
            if (j) s1 = fmaf(h1b[5 + j], w1[5 + j], s1);
        }
        float a = actf(s0 + s1);
        float gi = qb<0x00>(a), gf = qb<0x55>(a), gg = qb<0xAA>(a), go = qb<0xFF>(a);
        c1 = fmaf(gf, c1, gi * gg);
        float h1u = go * ctanh(c1);
        #pragma unroll
        for (int j = 0; j < HID; ++j) h1b[j] = bp(baddr[j], h1u);
        float q0 = b2;
        float q1 = h1b[5] * wi2[5];
        float q2 = h2b[0] * wh2[0];
        float q3 = h2b[5] * wh2[5];
        #pragma unroll
        for (int j = 0; j < 5; ++j) {
            q0 = fmaf(h1b[j], wi2[j], q0);
            if (j) q1 = fmaf(h1b[5 + j], wi2[5 + j], q1);
            if (j) q2 = fmaf(h2b[j],     wh2[j],     q2);
            if (j) q3 = fmaf(h2b[5 + j], wh2[5 + j], q3);
        }
        float d = actf((q0 + q1) + (q2 + q3));
        float qi = qb<0x00>(d), qf = qb<0x55>(d), qg = qb<0xAA>(d), qo = qb<0xFF>(d);
        c2 = fmaf(qf, c2, qi * qg);
        float h2u = qo * ctanh(c2);
        #pragma unroll
        for (int j = 0; j < HID; ++j) h2b[j] = bp(baddr[j], h2u);
        float y0 = fmaf(h2b[0], wl[0], bl);
        float y1 = h2b[5] * wl[5];
        #pragma unroll
        for (int j = 1; j < 5; ++j) {
            y0 = fmaf(h2b[j], wl[j], y0);
            y1 = fmaf(h2b[5 + j], wl[5 + j], y1);
        }
        return y0 + y1;
    };

    // ---- prologue: cell1 steps 1,2 (consume x[0], x[1]) ----
    const float4* xrow = (const float4*)(x + (size_t)ge * TMAIN);  // wave-uniform
    float4 xa = xrow[0];
    c1_iter(xa.x);      // h1(1); h1o = h1(0) = 0
    c1_iter(xa.y);      // h1(2); h1o = h1(1)

    // ---- steady: g = 0..254 cover n = 4g+2 .. 4g+5  (n = 2..1021) ----
    #pragma unroll 1
    for (int g = 0; g < TMAIN / 4 - 1; ++g) {
        float4 xb = xrow[g + 1];
        int n = 4 * g + 2;
        full_iter(xa.z, n - 3);
        full_iter(xa.w, n - 2);
        full_iter(xb.x, n - 1);
        full_iter(xb.y, n);
        xa = xb;
    }
    // ---- epilogue ----
    full_iter(xa.z, 1019);          // n=1022
    full_iter(xa.w, 1020);          // n=1023: h1(1024), h2(1022)
    c2_iter(h1o, 1021);             // h2(1023), y(1022)
    c2_iter(h1b, 1022);             // h2(1024), y(1023)
    {
        float y0 = fmaf(h2b[0], wl[0], bl);
        float y1 = h2b[5] * wl[5];
        #pragma unroll
        for (int j = 1; j < 5; ++j) {
            y0 = fmaf(h2b[j], wl[j], y0);
            y1 = fmaf(h2b[5 + j], wl[5 + j], y1);
        }
        float ylast = y0 + y1;                 // y(1024)
        if (st) orow[TMAIN - 1] = ylast;
        // ---- future loop: serial; state = step-1024 everywhere ----
        float yprev = ylast;
        #pragma unroll 1
        for (int t = 0; t < F; ++t) {
            yprev = fstep(yprev);
            if (st) orow[TMAIN + t] = yprev;
        }
    }
}

extern "C" void kernel_launch(void* const* d_in, const int* in_sizes, int n_in,
                              void* d_out, int out_size, void* d_ws, size_t ws_size,
                              hipStream_t stream) {
    const float* x    = (const float*)d_in[0];
    const float* Wih1 = (const float*)d_in[1];
    const float* Whh1 = (const float*)d_in[2];
    const float* bih1 = (const float*)d_in[3];
    const float* bhh1 = (const float*)d_in[4];
    const float* Wih2 = (const float*)d_in[5];
    const float* Whh2 = (const float*)d_in[6];
    const float* bih2 = (const float*)d_in[7];
    const float* bhh2 = (const float*)d_in[8];
    const float* Wlin = (const float*)d_in[9];
    const float* blin = (const float*)d_in[10];
    const int*   futp = (const int*)d_in[11];
    float* out = (float*)d_out;

    lstm2_kernel<<<NB, 64, 0, stream>>>(x, Wih1, Whh1, bih1, bhh1,
                                        Wih2, Whh2, bih2, bhh2,
                                        Wlin, blin, futp, out);
}